// Round 6
// baseline (681.939 us; speedup 1.0000x reference)
//
#include <hip/hip_runtime.h>
#include <stdint.h>

typedef unsigned short ushort_t;
typedef unsigned char u8_t;
typedef __attribute__((ext_vector_type(8))) short bf16x8;
typedef __attribute__((ext_vector_type(4))) float f32x4;
typedef __attribute__((ext_vector_type(4))) unsigned int u32x4;

#define NTOK 49
#define DIMC 192
#define NH 6
#define HD 32
#define XS 200      // x/q/k/ao row stride (bf16 elems; 400B -> 16B-aligned rows)
#define VTS 72      // vT row stride (tokens; 144B aligned)
#define PS 72       // P row stride
#define MS 66       // mask row stride (u16 bf16)
#define RS8 68      // rel row stride (u8)

// LDS carve (bytes), all 16B aligned; total 162,592 <= 163,840
#define OFF_X    0          // [64][200] bf16 : x, later attn-out (ao)
#define OFF_Q    25600      // [64][200] bf16
#define OFF_K    51200      // [64][200] bf16
#define OFF_VT   76800      // [192][72] bf16 : vT rows = h*32+dim, cols = token
#define OFF_P    104448     // [16][16][72] bf16 : per-wave probabilities
#define OFF_MASK 141312     // [64][66] bf16 (0 / -100 exact)
#define OFF_RPB  149760     // [169][8] f32
#define OFF_REL  155168     // [64][68] u8 (values < 169)
#define OFF_BQ   159520     // [576] f32
#define OFF_BP   161824     // [192] f32
#define SMEM_BYTES 162592

#define QKVW_N (576 * 192)
#define PROJW_N (192 * 192)
#define WS_NEED ((QKVW_N + PROJW_N) * 2)   // bf16 weights in d_ws

__device__ __forceinline__ float bf2f(ushort_t u) {
    return __builtin_bit_cast(float, (uint32_t)u << 16);
}
__device__ __forceinline__ ushort_t f2bf(float f) {
    uint32_t x = __builtin_bit_cast(uint32_t, f);
    x += 0x7fffu + ((x >> 16) & 1u);   // RNE
    return (ushort_t)(x >> 16);
}

__device__ __forceinline__ bf16x8 cvt8(const float* p) {
    f32x4 a = *(const f32x4*)p;
    f32x4 b = *(const f32x4*)(p + 4);
    bf16x8 r;
    r[0] = (short)f2bf(a[0]); r[1] = (short)f2bf(a[1]);
    r[2] = (short)f2bf(a[2]); r[3] = (short)f2bf(a[3]);
    r[4] = (short)f2bf(b[0]); r[5] = (short)f2bf(b[1]);
    r[6] = (short)f2bf(b[2]); r[7] = (short)f2bf(b[3]);
    return r;
}

// ---- pre-pass: f32 weights -> bf16 in workspace ----
__global__ __launch_bounds__(256) void cvt_weights_kernel(
    const float* __restrict__ qkvw, const float* __restrict__ projw,
    ushort_t* __restrict__ dst)
{
    int i = (blockIdx.x * 256 + threadIdx.x) * 8;
    if (i >= QKVW_N + PROJW_N) return;
    const float* src = (i < QKVW_N) ? (qkvw + i) : (projw + (i - QKVW_N));
    f32x4 a = *(const f32x4*)src;
    f32x4 b = *(const f32x4*)(src + 4);
    u32x4 o;
    o[0] = (uint32_t)f2bf(a[0]) | ((uint32_t)f2bf(a[1]) << 16);
    o[1] = (uint32_t)f2bf(a[2]) | ((uint32_t)f2bf(a[3]) << 16);
    o[2] = (uint32_t)f2bf(b[0]) | ((uint32_t)f2bf(b[1]) << 16);
    o[3] = (uint32_t)f2bf(b[2]) | ((uint32_t)f2bf(b[3]) << 16);
    *(u32x4*)(dst + i) = o;
}

template <bool WBF>
__global__ __launch_bounds__(1024) void win_attn_kernel(
    const float* __restrict__ x_g,
    const float* __restrict__ mask_g,
    const float* __restrict__ rpb_g,
    const int* __restrict__ rel_g,
    const float* __restrict__ qkvw_g,
    const float* __restrict__ qkvb_g,
    const float* __restrict__ projw_g,
    const float* __restrict__ projb_g,
    const ushort_t* __restrict__ wbf_g,   // bf16 [qkvw | projw] in ws (if WBF)
    float* __restrict__ out_g)
{
    extern __shared__ char smem[];
    ushort_t* x_lds  = (ushort_t*)(smem + OFF_X);
    ushort_t* q_lds  = (ushort_t*)(smem + OFF_Q);
    ushort_t* k_lds  = (ushort_t*)(smem + OFF_K);
    ushort_t* vT     = (ushort_t*)(smem + OFF_VT);
    ushort_t* P_lds  = (ushort_t*)(smem + OFF_P);
    ushort_t* mask_p = (ushort_t*)(smem + OFF_MASK);
    float*    rpb_l  = (float*)(smem + OFF_RPB);
    u8_t*     rel_p  = (u8_t*)(smem + OFF_REL);
    float*    bq     = (float*)(smem + OFF_BQ);
    float*    bp     = (float*)(smem + OFF_BP);

    const int tid  = threadIdx.x;
    const int b    = blockIdx.x;
    const int wi   = b & 63;           // window index -> mask row
    const int w    = tid >> 6;         // wave id 0..15
    const int lane = tid & 63;
    const int g    = lane >> 4;        // 16-lane group 0..3
    const int c    = lane & 15;        // lane-in-group

    // ---------------- stage ----------------
    {
        const float* xg = x_g + (size_t)b * (NTOK * DIMC);
        for (int i = tid; i < 64 * 24; i += 1024) {          // 64 rows x 24 chunks of 8
            int row = i / 24, col = (i % 24) * 8;
            u32x4 v = {0u, 0u, 0u, 0u};
            if (row < NTOK) {
                const float* src = xg + row * DIMC + col;
                f32x4 a = *(const f32x4*)src;
                f32x4 d = *(const f32x4*)(src + 4);
                v[0] = (uint32_t)f2bf(a[0]) | ((uint32_t)f2bf(a[1]) << 16);
                v[1] = (uint32_t)f2bf(a[2]) | ((uint32_t)f2bf(a[3]) << 16);
                v[2] = (uint32_t)f2bf(d[0]) | ((uint32_t)f2bf(d[1]) << 16);
                v[3] = (uint32_t)f2bf(d[2]) | ((uint32_t)f2bf(d[3]) << 16);
            }
            *(u32x4*)&x_lds[row * XS + col] = v;
        }
        const float* mw = mask_g + (size_t)wi * (NTOK * NTOK);
        for (int i = tid; i < 64 * 64; i += 1024) {
            int m = i >> 6, n = i & 63;
            float f;
            if (n >= NTOK)      f = -30000.0f;               // masked padded keys
            else if (m >= NTOK) f = 0.0f;                    // padded queries: finite
            else                f = mw[m * NTOK + n];
            mask_p[m * MS + n] = f2bf(f);                    // 0 / -100 exact in bf16
            rel_p[m * RS8 + n] = (m < NTOK && n < NTOK) ? (u8_t)rel_g[m * NTOK + n]
                                                        : (u8_t)0;
        }
        if (tid < 169 * 6)
            rpb_l[(tid / 6) * 8 + (tid % 6)] = rpb_g[tid];
        if (tid < 576) bq[tid] = qkvb_g[tid];
        if (tid < 192) bp[tid] = projb_g[tid];
    }
    __syncthreads();

    // ---------------- QKV GEMM: [64,192] @ [192,576] ----------------
    // wave (m4 = w&3, cq = w>>2): rows [16*m4,+16), cols [144*cq,+144) = 9 tiles
    {
        const int m4 = w & 3, cq = w >> 2;

        bf16x8 ring[2][6];               // depth-2 weight prefetch ring (WBF path)
        if constexpr (WBF) {
            const size_t col0 = (size_t)(144 * cq + c) * DIMC;
            #pragma unroll
            for (int kk = 0; kk < 6; ++kk)
                ring[0][kk] = *(const bf16x8*)(wbf_g + col0 + kk * 32 + g * 8);
        }

        bf16x8 ax[6];
        #pragma unroll
        for (int kk = 0; kk < 6; ++kk)
            ax[kk] = *(const bf16x8*)&x_lds[(16 * m4 + c) * XS + kk * 32 + g * 8];

        #pragma unroll
        for (int nt = 0; nt < 9; ++nt) {
            const int cg = 144 * cq + nt * 16 + c;           // output column (per-lane)
            bf16x8 bw[6];
            if constexpr (WBF) {
                if (nt + 1 < 9) {                            // prefetch next tile
                    const size_t col = (size_t)(144 * cq + (nt + 1) * 16 + c) * DIMC;
                    #pragma unroll
                    for (int kk = 0; kk < 6; ++kk)
                        ring[(nt + 1) & 1][kk] = *(const bf16x8*)(wbf_g + col + kk * 32 + g * 8);
                }
                #pragma unroll
                for (int kk = 0; kk < 6; ++kk) bw[kk] = ring[nt & 1][kk];
            } else {
                #pragma unroll
                for (int kk = 0; kk < 6; ++kk)
                    bw[kk] = cvt8(qkvw_g + (size_t)cg * DIMC + kk * 32 + g * 8);
            }
            f32x4 acc = {0.f, 0.f, 0.f, 0.f};
            #pragma unroll
            for (int kk = 0; kk < 6; ++kk)
                acc = __builtin_amdgcn_mfma_f32_16x16x32_bf16(ax[kk], bw[kk], acc, 0, 0, 0);

            const float bias = bq[cg];
            const int seg = 144 * cq + nt * 16;              // wave-uniform segment base
            if (seg < 192) {            // q
                #pragma unroll
                for (int r = 0; r < 4; ++r)
                    q_lds[(16 * m4 + g * 4 + r) * XS + cg] = f2bf(acc[r] + bias);
            } else if (seg < 384) {     // k
                const int ck = cg - 192;
                #pragma unroll
                for (int r = 0; r < 4; ++r)
                    k_lds[(16 * m4 + g * 4 + r) * XS + ck] = f2bf(acc[r] + bias);
            } else {                    // v -> transposed store vT[h*32+dim][token]
                const int cv = cg - 384;
                uint32_t lo = (uint32_t)f2bf(acc[0] + bias) | ((uint32_t)f2bf(acc[1] + bias) << 16);
                uint32_t hi = (uint32_t)f2bf(acc[2] + bias) | ((uint32_t)f2bf(acc[3] + bias) << 16);
                uint32_t* dst = (uint32_t*)&vT[cv * VTS + 16 * m4 + g * 4];
                dst[0] = lo; dst[1] = hi;
            }
        }
    }
    __syncthreads();

    // ---------------- attention: 24 items (ws = it&3 q-strip, h = it>>2), striped over 16 waves ----
    {
        ushort_t* Pw = P_lds + w * (16 * PS);                // per-wave slot
        for (int it = w; it < 24; it += 16) {
            const int ws = it & 3, h = it >> 2;
            const int mq0 = 16 * ws + g * 4;
            // S = q . k^T  (strip [16] x keys [64])
            bf16x8 aq = *(const bf16x8*)&q_lds[(16 * ws + c) * XS + h * HD + g * 8];
            f32x4 S[4];
            #pragma unroll
            for (int t = 0; t < 4; ++t) {
                bf16x8 bk = *(const bf16x8*)&k_lds[(16 * t + c) * XS + h * HD + g * 8];
                f32x4 z = {0.f, 0.f, 0.f, 0.f};
                S[t] = __builtin_amdgcn_mfma_f32_16x16x32_bf16(aq, bk, z, 0, 0, 0);
            }
            // softmax over 64 keys (rows mq0+r)
            #pragma unroll
            for (int r = 0; r < 4; ++r) {
                const int mq = mq0 + r;
                const ushort_t* mrow = mask_p + mq * MS;
                const u8_t*     rrow = rel_p + mq * RS8;
                float sv[4];
                float vmax = -3e38f;
                #pragma unroll
                for (int t = 0; t < 4; ++t) {
                    const int n = 16 * t + c;
                    float s = S[t][r] * 0.17677669529663687f
                            + rpb_l[(int)rrow[n] * 8 + h] + bf2f(mrow[n]);
                    sv[t] = s;
                    vmax = fmaxf(vmax, s);
                }
                #pragma unroll
                for (int xm = 1; xm < 16; xm <<= 1)
                    vmax = fmaxf(vmax, __shfl_xor(vmax, xm));
                float sum = 0.f;
                float ev[4];
                #pragma unroll
                for (int t = 0; t < 4; ++t) {
                    ev[t] = __expf(fmaxf(sv[t] - vmax, -80.0f));   // NaN firewall
                    sum += ev[t];
                }
                #pragma unroll
                for (int xm = 1; xm < 16; xm <<= 1)
                    sum += __shfl_xor(sum, xm);
                const float rinv = 1.0f / sum;
                #pragma unroll
                for (int t = 0; t < 4; ++t)
                    Pw[(g * 4 + r) * PS + 16 * t + c] = f2bf(ev[t] * rinv);
            }
            // O = P @ V   (A = P[16x64], B = vT rows) — same-wave LDS dep, no barrier
            f32x4 z = {0.f, 0.f, 0.f, 0.f};
            f32x4 O[2] = {z, z};
            #pragma unroll
            for (int ks = 0; ks < 2; ++ks) {
                bf16x8 ap = *(const bf16x8*)&Pw[c * PS + ks * 32 + g * 8];
                #pragma unroll
                for (int nt = 0; nt < 2; ++nt) {
                    bf16x8 bv = *(const bf16x8*)&vT[(h * HD + nt * 16 + c) * VTS + ks * 32 + g * 8];
                    O[nt] = __builtin_amdgcn_mfma_f32_16x16x32_bf16(ap, bv, O[nt], 0, 0, 0);
                }
            }
            // ao (reuse x_lds); items write disjoint (ws rows x head cols)
            #pragma unroll
            for (int nt = 0; nt < 2; ++nt)
                #pragma unroll
                for (int r = 0; r < 4; ++r)
                    x_lds[(16 * ws + g * 4 + r) * XS + h * HD + nt * 16 + c] = f2bf(O[nt][r]);
        }
    }
    __syncthreads();

    // ---------------- proj GEMM: [64,192] @ [192,192] -> direct f32 global store ----------------
    // wave (m4 = w&3, cq = w>>2): rows [16*m4,+16), cols [48*cq,+48)
    {
        const int m4 = w & 3, cq = w >> 2;
        bf16x8 aa[6];
        #pragma unroll
        for (int kk = 0; kk < 6; ++kk)
            aa[kk] = *(const bf16x8*)&x_lds[(16 * m4 + c) * XS + kk * 32 + g * 8];

        float* og = out_g + (size_t)b * (NTOK * DIMC);
        #pragma unroll
        for (int nt = 0; nt < 3; ++nt) {
            const int cg = 48 * cq + nt * 16 + c;
            bf16x8 bw[6];
            #pragma unroll
            for (int kk = 0; kk < 6; ++kk) {
                if constexpr (WBF)
                    bw[kk] = *(const bf16x8*)(wbf_g + (size_t)QKVW_N + (size_t)cg * DIMC + kk * 32 + g * 8);
                else
                    bw[kk] = cvt8(projw_g + (size_t)cg * DIMC + kk * 32 + g * 8);
            }
            f32x4 acc = {0.f, 0.f, 0.f, 0.f};
            #pragma unroll
            for (int kk = 0; kk < 6; ++kk)
                acc = __builtin_amdgcn_mfma_f32_16x16x32_bf16(aa[kk], bw[kk], acc, 0, 0, 0);
            const float bias = bp[cg];
            #pragma unroll
            for (int r = 0; r < 4; ++r) {
                const int row = 16 * m4 + g * 4 + r;
                if (row < NTOK) og[row * DIMC + cg] = acc[r] + bias;
            }
        }
    }
}

extern "C" void kernel_launch(void* const* d_in, const int* in_sizes, int n_in,
                              void* d_out, int out_size, void* d_ws, size_t ws_size,
                              hipStream_t stream) {
    (void)in_sizes; (void)n_in; (void)out_size;
    const float* x_g     = (const float*)d_in[0];
    const float* mask_g  = (const float*)d_in[1];
    const float* rpb_g   = (const float*)d_in[2];
    const int*   rel_g   = (const int*)d_in[3];
    const float* qkvw_g  = (const float*)d_in[4];
    const float* qkvb_g  = (const float*)d_in[5];
    const float* projw_g = (const float*)d_in[6];
    const float* projb_g = (const float*)d_in[7];
    float*       out_g   = (float*)d_out;

    const bool use_ws = (ws_size >= (size_t)WS_NEED) && (d_ws != nullptr);
    if (use_ws) {
        ushort_t* wbf = (ushort_t*)d_ws;
        int nblk = (QKVW_N + PROJW_N) / 8 / 256;   // 72
        hipLaunchKernelGGL(cvt_weights_kernel, dim3(nblk), dim3(256), 0, stream,
                           qkvw_g, projw_g, wbf);
        hipFuncSetAttribute((const void*)win_attn_kernel<true>,
                            hipFuncAttributeMaxDynamicSharedMemorySize, SMEM_BYTES);
        hipLaunchKernelGGL(win_attn_kernel<true>, dim3(4096), dim3(1024), SMEM_BYTES, stream,
                           x_g, mask_g, rpb_g, rel_g, qkvw_g, qkvb_g, projw_g, projb_g,
                           wbf, out_g);
    } else {
        hipFuncSetAttribute((const void*)win_attn_kernel<false>,
                            hipFuncAttributeMaxDynamicSharedMemorySize, SMEM_BYTES);
        hipLaunchKernelGGL(win_attn_kernel<false>, dim3(4096), dim3(1024), SMEM_BYTES, stream,
                           x_g, mask_g, rpb_g, rel_g, qkvw_g, qkvb_g, projw_g, projb_g,
                           (const ushort_t*)nullptr, out_g);
    }
}

// Round 7
// 327.608 us; speedup vs baseline: 2.0816x; 2.0816x over previous
//
#include <hip/hip_runtime.h>
#include <stdint.h>

typedef unsigned short ushort_t;
typedef __attribute__((ext_vector_type(8))) short bf16x8;
typedef __attribute__((ext_vector_type(4))) float f32x4;
typedef __attribute__((ext_vector_type(4))) unsigned int u32x4;

#define NTOK 49
#define DIMC 192
#define NH 6
#define HD 32
#define XS 200      // x/q/k/ao row stride (bf16 elems)
#define VTS 72      // vT row stride (tokens)
#define PS 72       // P row stride
#define MS 66       // mask row stride (f32)
#define RS 68       // rel row stride (u16)

// LDS carve (bytes), all 16B aligned
#define OFF_X    0          // [64][200] bf16 : x, later attn-out (ao)
#define OFF_Q    25600      // [64][200] bf16
#define OFF_K    51200      // [64][200] bf16
#define OFF_VT   76800      // [192][72] bf16 : vT rows = h*32+dim, cols = token
#define OFF_P    104448     // [8][16][72] bf16 : per-wave probabilities
#define OFF_MASK 122880     // [64][66] f32
#define OFF_RPB  139776     // [169][8] f32
#define OFF_REL  145184     // [64][68] u16
#define OFF_BQ   153888     // [576] f32
#define OFF_BP   156192     // [192] f32
#define SMEM_BYTES 156960

#define QKVW_N (576 * 192)              // 110592
#define PROJW_N (192 * 192)             // 36864
#define QKV_GRP (4 * 9 * 6 * 64)        // 13824 groups of 8 elems
#define PROJ_GRP (4 * 3 * 6 * 64)       // 4608
#define WS_NEED ((QKVW_N + PROJW_N) * 2)

__device__ __forceinline__ ushort_t f2bf(float f) {
    uint32_t x = __builtin_bit_cast(uint32_t, f);
    x += 0x7fffu + ((x >> 16) & 1u);   // RNE
    return (ushort_t)(x >> 16);
}

__device__ __forceinline__ bf16x8 cvt8(const float* p) {
    f32x4 a = *(const f32x4*)p;
    f32x4 b = *(const f32x4*)(p + 4);
    bf16x8 r;
    r[0] = (short)f2bf(a[0]); r[1] = (short)f2bf(a[1]);
    r[2] = (short)f2bf(a[2]); r[3] = (short)f2bf(a[3]);
    r[4] = (short)f2bf(b[0]); r[5] = (short)f2bf(b[1]);
    r[6] = (short)f2bf(b[2]); r[7] = (short)f2bf(b[3]);
    return r;
}

// ---- pre-pass: f32 weights -> bf16 in MFMA-fragment-swizzled order ----
// QKV block: group index i in [0, QKV_GRP): lane=i&63, kk=(i>>6)%6,
//   nt=((i>>6)/6)%9, cq=(i>>6)/54. col=cq*144+nt*16+(lane&15), k0=kk*32+(lane>>4)*8.
// Wave load of tile (cq,nt,kk): lane reads dst[((cq*9+nt)*6+kk)*64*8 + lane*8] -> coalesced 1KB.
__global__ __launch_bounds__(256) void swz_weights_kernel(
    const float* __restrict__ qkvw, const float* __restrict__ projw,
    ushort_t* __restrict__ dst)
{
    int i = blockIdx.x * 256 + threadIdx.x;
    if (i >= QKV_GRP + PROJ_GRP) return;
    const float* src;
    if (i < QKV_GRP) {
        int lane = i & 63, t = i >> 6;
        int kk = t % 6, nt = (t / 6) % 9, cq = t / 54;
        int col = cq * 144 + nt * 16 + (lane & 15);
        int k0 = kk * 32 + (lane >> 4) * 8;
        src = qkvw + col * DIMC + k0;
    } else {
        int j = i - QKV_GRP;
        int lane = j & 63, t = j >> 6;
        int kk = t % 6, nt = (t / 6) % 3, cq = t / 18;
        int col = cq * 48 + nt * 16 + (lane & 15);
        int k0 = kk * 32 + (lane >> 4) * 8;
        src = projw + col * DIMC + k0;
    }
    f32x4 a = *(const f32x4*)src;
    f32x4 b = *(const f32x4*)(src + 4);
    u32x4 o;
    o[0] = (uint32_t)f2bf(a[0]) | ((uint32_t)f2bf(a[1]) << 16);
    o[1] = (uint32_t)f2bf(a[2]) | ((uint32_t)f2bf(a[3]) << 16);
    o[2] = (uint32_t)f2bf(b[0]) | ((uint32_t)f2bf(b[1]) << 16);
    o[3] = (uint32_t)f2bf(b[2]) | ((uint32_t)f2bf(b[3]) << 16);
    *(u32x4*)(dst + (size_t)i * 8) = o;
}

template <bool WBF>
__global__ __launch_bounds__(512, 1) void win_attn_kernel(
    const float* __restrict__ x_g,
    const float* __restrict__ mask_g,
    const float* __restrict__ rpb_g,
    const int* __restrict__ rel_g,
    const float* __restrict__ qkvw_g,
    const float* __restrict__ qkvb_g,
    const float* __restrict__ projw_g,
    const float* __restrict__ projb_g,
    const ushort_t* __restrict__ wbf_g,   // swizzled bf16 [qkvw | projw] in ws
    float* __restrict__ out_g)
{
    extern __shared__ char smem[];
    ushort_t* x_lds  = (ushort_t*)(smem + OFF_X);
    ushort_t* q_lds  = (ushort_t*)(smem + OFF_Q);
    ushort_t* k_lds  = (ushort_t*)(smem + OFF_K);
    ushort_t* vT     = (ushort_t*)(smem + OFF_VT);
    ushort_t* P_lds  = (ushort_t*)(smem + OFF_P);
    float*    mask_p = (float*)(smem + OFF_MASK);
    float*    rpb_l  = (float*)(smem + OFF_RPB);
    ushort_t* rel_p  = (ushort_t*)(smem + OFF_REL);
    float*    bq     = (float*)(smem + OFF_BQ);
    float*    bp     = (float*)(smem + OFF_BP);

    const int tid  = threadIdx.x;
    const int b    = blockIdx.x;
    const int wi   = b & 63;           // window index -> mask row
    const int w    = tid >> 6;         // wave id 0..7
    const int lane = tid & 63;
    const int g    = lane >> 4;        // 16-lane group 0..3
    const int c    = lane & 15;        // lane-in-group

    // ---------------- stage ----------------
    {
        const float* xg = x_g + (size_t)b * (NTOK * DIMC);
        for (int i = tid; i < 64 * 24; i += 512) {           // 64 rows x 24 chunks of 8
            int row = i / 24, col = (i % 24) * 8;
            u32x4 v = {0u, 0u, 0u, 0u};
            if (row < NTOK) {
                const float* src = xg + row * DIMC + col;
                f32x4 a = *(const f32x4*)src;
                f32x4 d = *(const f32x4*)(src + 4);
                v[0] = (uint32_t)f2bf(a[0]) | ((uint32_t)f2bf(a[1]) << 16);
                v[1] = (uint32_t)f2bf(a[2]) | ((uint32_t)f2bf(a[3]) << 16);
                v[2] = (uint32_t)f2bf(d[0]) | ((uint32_t)f2bf(d[1]) << 16);
                v[3] = (uint32_t)f2bf(d[2]) | ((uint32_t)f2bf(d[3]) << 16);
            }
            *(u32x4*)&x_lds[row * XS + col] = v;
        }
        const float* mw = mask_g + (size_t)wi * (NTOK * NTOK);
        for (int i = tid; i < 64 * 64; i += 512) {
            int m = i >> 6, n = i & 63;
            float f;
            if (n >= NTOK)      f = -30000.0f;               // masked padded keys
            else if (m >= NTOK) f = 0.0f;                    // padded queries: finite
            else                f = mw[m * NTOK + n];
            mask_p[m * MS + n] = f;
            rel_p[m * RS + n] = (m < NTOK && n < NTOK) ? (ushort_t)rel_g[m * NTOK + n]
                                                       : (ushort_t)0;
        }
        for (int i = tid; i < 169 * 6; i += 512)
            rpb_l[(i / 6) * 8 + (i % 6)] = rpb_g[i];
        for (int i = tid; i < 576; i += 512) bq[i] = qkvb_g[i];
        if (tid < 192) bp[tid] = projb_g[tid];
    }
    __syncthreads();

    // ---------------- QKV GEMM: [64,192] @ [192,576] ----------------
    // wave (mh = w>>2, cq = w&3): rows [32mh,+32), cols [144cq,+144) = 9 tiles
    // WBF: depth-4 register ring, swizzled-coalesced loads, sched_barrier pins.
    {
        const int mh = w >> 2, cq = w & 3;
        const ushort_t* wq = wbf_g + (size_t)cq * (9 * 6 * 64 * 8);

        bf16x8 ring[4][6];
        if constexpr (WBF) {
            #pragma unroll
            for (int p = 0; p < 3; ++p)
                #pragma unroll
                for (int kk = 0; kk < 6; ++kk)
                    ring[p][kk] = *(const bf16x8*)(wq + (size_t)((p * 6 + kk) * 64 + lane) * 8);
            __builtin_amdgcn_sched_barrier(0);   // pin: prefetch issued before anything below
        }

        bf16x8 ax[2][6];
        #pragma unroll
        for (int mt = 0; mt < 2; ++mt)
            #pragma unroll
            for (int kk = 0; kk < 6; ++kk)
                ax[mt][kk] = *(const bf16x8*)&x_lds[(32 * mh + 16 * mt + c) * XS + kk * 32 + g * 8];

        #pragma unroll
        for (int nt = 0; nt < 9; ++nt) {
            const int cg = 144 * cq + nt * 16 + c;           // output column (per-lane)
            bf16x8 bw[6];
            if constexpr (WBF) {
                if (nt + 3 < 9) {                            // issue tile nt+3
                    #pragma unroll
                    for (int kk = 0; kk < 6; ++kk)
                        ring[(nt + 3) & 3][kk] =
                            *(const bf16x8*)(wq + (size_t)(((nt + 3) * 6 + kk) * 64 + lane) * 8);
                }
                __builtin_amdgcn_sched_barrier(0);           // pin: loads stay above compute
                #pragma unroll
                for (int kk = 0; kk < 6; ++kk) bw[kk] = ring[nt & 3][kk];
            } else {
                #pragma unroll
                for (int kk = 0; kk < 6; ++kk)
                    bw[kk] = cvt8(qkvw_g + (size_t)cg * DIMC + kk * 32 + g * 8);
            }
            f32x4 z = {0.f, 0.f, 0.f, 0.f};
            f32x4 acc[2] = {z, z};
            #pragma unroll
            for (int kk = 0; kk < 6; ++kk)
                #pragma unroll
                for (int mt = 0; mt < 2; ++mt)
                    acc[mt] = __builtin_amdgcn_mfma_f32_16x16x32_bf16(ax[mt][kk], bw[kk], acc[mt], 0, 0, 0);

            const float bias = bq[cg];
            const int seg = 144 * cq + nt * 16;              // wave-uniform segment base
            if (seg < 192) {            // q
                #pragma unroll
                for (int mt = 0; mt < 2; ++mt)
                    #pragma unroll
                    for (int r = 0; r < 4; ++r)
                        q_lds[(32 * mh + 16 * mt + g * 4 + r) * XS + cg] = f2bf(acc[mt][r] + bias);
            } else if (seg < 384) {     // k
                const int ck = cg - 192;
                #pragma unroll
                for (int mt = 0; mt < 2; ++mt)
                    #pragma unroll
                    for (int r = 0; r < 4; ++r)
                        k_lds[(32 * mh + 16 * mt + g * 4 + r) * XS + ck] = f2bf(acc[mt][r] + bias);
            } else {                    // v -> transposed store vT[h*32+dim][token]
                const int cv = cg - 384;
                #pragma unroll
                for (int mt = 0; mt < 2; ++mt) {
                    uint32_t lo = (uint32_t)f2bf(acc[mt][0] + bias) | ((uint32_t)f2bf(acc[mt][1] + bias) << 16);
                    uint32_t hi = (uint32_t)f2bf(acc[mt][2] + bias) | ((uint32_t)f2bf(acc[mt][3] + bias) << 16);
                    uint32_t* dst = (uint32_t*)&vT[cv * VTS + 32 * mh + 16 * mt + g * 4];
                    dst[0] = lo; dst[1] = hi;
                }
            }
        }
    }
    __syncthreads();

    // ---------------- attention: wave (ws = w&3, hh = w>>2): q-strip [16ws,+16), heads [3hh,+3) ----
    // Proj weights prefetched (swizzled, coalesced) at phase start; complete during attention.
    bf16x8 pw[3][6];
    {
        if constexpr (WBF) {
            const int cq4 = w & 3;
            const ushort_t* wp = wbf_g + QKVW_N + (size_t)cq4 * (3 * 6 * 64 * 8);
            #pragma unroll
            for (int nt = 0; nt < 3; ++nt)
                #pragma unroll
                for (int kk = 0; kk < 6; ++kk)
                    pw[nt][kk] = *(const bf16x8*)(wp + (size_t)((nt * 6 + kk) * 64 + lane) * 8);
            __builtin_amdgcn_sched_barrier(0);   // pin: issue before attention compute
        }

        const int ws = w & 3, hh = w >> 2;
        ushort_t* Pw = P_lds + w * (16 * PS);
        const int mq0 = 16 * ws + g * 4;
        #pragma unroll 1
        for (int hi = 0; hi < 3; ++hi) {
            const int h = hh * 3 + hi;
            // S = q . k^T  (strip [16] x keys [64])
            bf16x8 aq = *(const bf16x8*)&q_lds[(16 * ws + c) * XS + h * HD + g * 8];
            f32x4 S[4];
            #pragma unroll
            for (int t = 0; t < 4; ++t) {
                bf16x8 bk = *(const bf16x8*)&k_lds[(16 * t + c) * XS + h * HD + g * 8];
                f32x4 z = {0.f, 0.f, 0.f, 0.f};
                S[t] = __builtin_amdgcn_mfma_f32_16x16x32_bf16(aq, bk, z, 0, 0, 0);
            }
            // softmax over 64 keys (rows mq0+r)
            #pragma unroll
            for (int r = 0; r < 4; ++r) {
                const int mq = mq0 + r;
                const float*    mrow = mask_p + mq * MS;
                const ushort_t* rrow = rel_p + mq * RS;
                float sv[4];
                float vmax = -3e38f;
                #pragma unroll
                for (int t = 0; t < 4; ++t) {
                    const int n = 16 * t + c;
                    float s = S[t][r] * 0.17677669529663687f
                            + rpb_l[(int)rrow[n] * 8 + h] + mrow[n];
                    sv[t] = s;
                    vmax = fmaxf(vmax, s);
                }
                #pragma unroll
                for (int xm = 1; xm < 16; xm <<= 1)
                    vmax = fmaxf(vmax, __shfl_xor(vmax, xm));
                float sum = 0.f;
                float ev[4];
                #pragma unroll
                for (int t = 0; t < 4; ++t) {
                    ev[t] = __expf(fmaxf(sv[t] - vmax, -80.0f));   // NaN firewall
                    sum += ev[t];
                }
                #pragma unroll
                for (int xm = 1; xm < 16; xm <<= 1)
                    sum += __shfl_xor(sum, xm);
                const float rinv = 1.0f / sum;
                #pragma unroll
                for (int t = 0; t < 4; ++t)
                    Pw[(g * 4 + r) * PS + 16 * t + c] = f2bf(ev[t] * rinv);
            }
            // O = P @ V   (A = P[16x64], B = vT rows)  — same-wave LDS dep, no barrier
            f32x4 z = {0.f, 0.f, 0.f, 0.f};
            f32x4 O[2] = {z, z};
            #pragma unroll
            for (int ks = 0; ks < 2; ++ks) {
                bf16x8 ap = *(const bf16x8*)&Pw[c * PS + ks * 32 + g * 8];
                #pragma unroll
                for (int nt = 0; nt < 2; ++nt) {
                    bf16x8 bv = *(const bf16x8*)&vT[(h * HD + nt * 16 + c) * VTS + ks * 32 + g * 8];
                    O[nt] = __builtin_amdgcn_mfma_f32_16x16x32_bf16(ap, bv, O[nt], 0, 0, 0);
                }
            }
            // ao (reuse x_lds); per-wave disjoint (ws rows x head cols)
            #pragma unroll
            for (int nt = 0; nt < 2; ++nt)
                #pragma unroll
                for (int r = 0; r < 4; ++r)
                    x_lds[(16 * ws + g * 4 + r) * XS + h * HD + nt * 16 + c] = f2bf(O[nt][r]);
        }
    }
    __syncthreads();

    // ---------------- proj GEMM: [64,192] @ [192,192] -> direct f32 global store ----------------
    // wave (mh = w>>2, cq4 = w&3): rows [32mh,+32), cols [48cq4,+48)
    {
        const int mh = w >> 2, cq4 = w & 3;
        bf16x8 aa[2][6];
        #pragma unroll
        for (int mt = 0; mt < 2; ++mt)
            #pragma unroll
            for (int kk = 0; kk < 6; ++kk)
                aa[mt][kk] = *(const bf16x8*)&x_lds[(32 * mh + 16 * mt + c) * XS + kk * 32 + g * 8];

        float* og = out_g + (size_t)b * (NTOK * DIMC);
        #pragma unroll
        for (int nt = 0; nt < 3; ++nt) {
            const int cg = 48 * cq4 + nt * 16 + c;
            bf16x8 bw[6];
            #pragma unroll
            for (int kk = 0; kk < 6; ++kk) {
                if constexpr (WBF)
                    bw[kk] = pw[nt][kk];                      // prefetched during attention
                else
                    bw[kk] = cvt8(projw_g + (size_t)cg * DIMC + kk * 32 + g * 8);
            }
            f32x4 z = {0.f, 0.f, 0.f, 0.f};
            f32x4 acc[2] = {z, z};
            #pragma unroll
            for (int kk = 0; kk < 6; ++kk)
                #pragma unroll
                for (int mt = 0; mt < 2; ++mt)
                    acc[mt] = __builtin_amdgcn_mfma_f32_16x16x32_bf16(aa[mt][kk], bw[kk], acc[mt], 0, 0, 0);
            const float bias = bp[cg];
            #pragma unroll
            for (int mt = 0; mt < 2; ++mt)
                #pragma unroll
                for (int r = 0; r < 4; ++r) {
                    const int row = 32 * mh + 16 * mt + g * 4 + r;
                    if (row < NTOK) og[row * DIMC + cg] = acc[mt][r] + bias;
                }
        }
    }
}

extern "C" void kernel_launch(void* const* d_in, const int* in_sizes, int n_in,
                              void* d_out, int out_size, void* d_ws, size_t ws_size,
                              hipStream_t stream) {
    (void)in_sizes; (void)n_in; (void)out_size;
    const float* x_g     = (const float*)d_in[0];
    const float* mask_g  = (const float*)d_in[1];
    const float* rpb_g   = (const float*)d_in[2];
    const int*   rel_g   = (const int*)d_in[3];
    const float* qkvw_g  = (const float*)d_in[4];
    const float* qkvb_g  = (const float*)d_in[5];
    const float* projw_g = (const float*)d_in[6];
    const float* projb_g = (const float*)d_in[7];
    float*       out_g   = (float*)d_out;

    const bool use_ws = (ws_size >= (size_t)WS_NEED) && (d_ws != nullptr);
    if (use_ws) {
        ushort_t* wbf = (ushort_t*)d_ws;
        int ngrp = QKV_GRP + PROJ_GRP;             // 18432
        hipLaunchKernelGGL(swz_weights_kernel, dim3((ngrp + 255) / 256), dim3(256), 0, stream,
                           qkvw_g, projw_g, wbf);
        hipFuncSetAttribute((const void*)win_attn_kernel<true>,
                            hipFuncAttributeMaxDynamicSharedMemorySize, SMEM_BYTES);
        hipLaunchKernelGGL(win_attn_kernel<true>, dim3(4096), dim3(512), SMEM_BYTES, stream,
                           x_g, mask_g, rpb_g, rel_g, qkvw_g, qkvb_g, projw_g, projb_g,
                           wbf, out_g);
    } else {
        hipFuncSetAttribute((const void*)win_attn_kernel<false>,
                            hipFuncAttributeMaxDynamicSharedMemorySize, SMEM_BYTES);
        hipLaunchKernelGGL(win_attn_kernel<false>, dim3(4096), dim3(512), SMEM_BYTES, stream,
                           x_g, mask_g, rpb_g, rel_g, qkvw_g, qkvb_g, projw_g, projb_g,
                           (const ushort_t*)nullptr, out_g);
    }
}

// Round 8
// 249.902 us; speedup vs baseline: 2.7288x; 1.3109x over previous
//
#include <hip/hip_runtime.h>
#include <stdint.h>

typedef unsigned short ushort_t;
typedef __attribute__((ext_vector_type(8))) short bf16x8;
typedef __attribute__((ext_vector_type(4))) float f32x4;
typedef __attribute__((ext_vector_type(4))) unsigned int u32x4;

#define NTOK 49
#define DIMC 192
#define NH 6
#define HD 32
#define SCALE 0.17677669529663687f
#define XS 200      // x/q/k/ao row stride (bf16 elems)
#define VTS 72      // vT row stride (tokens)
#define PS 72       // P row stride
#define MS 66       // mask row stride (f32)  [MODE<2 only]
#define RS 68       // rel row stride (u16)   [MODE<2 only]

// LDS carve (bytes), all 16B aligned
#define OFF_X    0          // [64][200] bf16 : x, later attn-out (ao)
#define OFF_Q    25600      // [64][200] bf16
#define OFF_K    51200      // [64][200] bf16
#define OFF_VT   76800      // [192][72] bf16 : vT rows = h*32+dim, cols = token
#define OFF_P    104448     // [8][16][72] bf16 : per-wave probabilities
#define OFF_MASK 122880     // [64][66] f32      [MODE<2]
#define OFF_RPB  139776     // [169][8] f32      [MODE<2]
#define OFF_REL  145184     // [64][68] u16      [MODE<2]
#define OFF_BQ   153888     // [576] f32
#define OFF_BP   156192     // [192] f32
#define SMEM_BYTES 156960

#define QKVW_N (576 * 192)              // 110592
#define PROJW_N (192 * 192)             // 36864
#define QKV_GRP (4 * 9 * 6 * 64)        // 13824 groups of 8 elems
#define PROJ_GRP (4 * 3 * 6 * 64)       // 4608
#define WBF_BYTES ((QKVW_N + PROJW_N) * 2)
#define BIAS_FLOATS (64 * 6 * 4 * 4 * 4 * 16 * 4)   // wi,h,ws,t,g,c,r = 1572864
#define WS_NEED1 ((size_t)WBF_BYTES)
#define WS_NEED2 ((size_t)WBF_BYTES + (size_t)BIAS_FLOATS * 4)

__device__ __forceinline__ ushort_t f2bf(float f) {
    uint32_t x = __builtin_bit_cast(uint32_t, f);
    x += 0x7fffu + ((x >> 16) & 1u);   // RNE
    return (ushort_t)(x >> 16);
}

__device__ __forceinline__ bf16x8 cvt8(const float* p) {
    f32x4 a = *(const f32x4*)p;
    f32x4 b = *(const f32x4*)(p + 4);
    bf16x8 r;
    r[0] = (short)f2bf(a[0]); r[1] = (short)f2bf(a[1]);
    r[2] = (short)f2bf(a[2]); r[3] = (short)f2bf(a[3]);
    r[4] = (short)f2bf(b[0]); r[5] = (short)f2bf(b[1]);
    r[6] = (short)f2bf(b[2]); r[7] = (short)f2bf(b[3]);
    return r;
}

// ---- pre-pass 1: f32 weights -> bf16, MFMA-fragment-swizzled; q-cols pre-scaled ----
__global__ __launch_bounds__(256) void swz_weights_kernel(
    const float* __restrict__ qkvw, const float* __restrict__ projw,
    ushort_t* __restrict__ dst)
{
    int i = blockIdx.x * 256 + threadIdx.x;
    if (i >= QKV_GRP + PROJ_GRP) return;
    const float* src;
    float s = 1.0f;
    if (i < QKV_GRP) {
        int lane = i & 63, t = i >> 6;
        int kk = t % 6, nt = (t / 6) % 9, cq = t / 54;
        int col = cq * 144 + nt * 16 + (lane & 15);
        int k0 = kk * 32 + (lane >> 4) * 8;
        src = qkvw + col * DIMC + k0;
        if (col < 192) s = SCALE;               // fold 1/sqrt(hd) into q-weights
    } else {
        int j = i - QKV_GRP;
        int lane = j & 63, t = j >> 6;
        int kk = t % 6, nt = (t / 6) % 3, cq = t / 18;
        int col = cq * 48 + nt * 16 + (lane & 15);
        int k0 = kk * 32 + (lane >> 4) * 8;
        src = projw + col * DIMC + k0;
    }
    f32x4 a = *(const f32x4*)src;
    f32x4 b = *(const f32x4*)(src + 4);
    u32x4 o;
    o[0] = (uint32_t)f2bf(a[0] * s) | ((uint32_t)f2bf(a[1] * s) << 16);
    o[1] = (uint32_t)f2bf(a[2] * s) | ((uint32_t)f2bf(a[3] * s) << 16);
    o[2] = (uint32_t)f2bf(b[0] * s) | ((uint32_t)f2bf(b[1] * s) << 16);
    o[3] = (uint32_t)f2bf(b[2] * s) | ((uint32_t)f2bf(b[3] * s) << 16);
    *(u32x4*)(dst + (size_t)i * 8) = o;
}

// ---- pre-pass 2: bias[wi][h][ws][t][g][c][r] = rpb[rel[m][n]][h] + mask[wi][m][n] ----
// m = 16*ws + 4*g + r (query), n = 16*t + c (key). Exact MFMA C-fragment order:
// lane = g*16+c loads f32x4 (r=0..3) -> wave load of one (wi,h,ws,t) chunk = coalesced 1KB.
__global__ __launch_bounds__(256) void bias_kernel(
    const float* __restrict__ mask_g, const float* __restrict__ rpb_g,
    const int* __restrict__ rel_g, float* __restrict__ dst)
{
    int i = blockIdx.x * 256 + threadIdx.x;          // [0, 393216)
    if (i >= BIAS_FLOATS / 4) return;
    int c = i & 15, g = (i >> 4) & 3, t = (i >> 6) & 3, wsid = (i >> 8) & 3;
    int hw = i >> 10;
    int h = hw % 6, wi = hw / 6;
    int m0 = 16 * wsid + 4 * g, n = 16 * t + c;
    f32x4 v;
    #pragma unroll
    for (int r = 0; r < 4; ++r) {
        int m = m0 + r;
        float val;
        if (n >= NTOK)      val = -30000.0f;
        else if (m >= NTOK) val = 0.0f;
        else val = mask_g[(size_t)wi * (NTOK * NTOK) + m * NTOK + n]
                 + rpb_g[(size_t)rel_g[m * NTOK + n] * NH + h];
        v[r] = val;
    }
    *(f32x4*)(dst + (size_t)i * 4) = v;
}

// MODE: 2 = swizzled weights + precomputed bias (full fast path)
//       1 = swizzled weights only (r7 path), 0 = raw f32 weights
template <int MODE>
__global__ __launch_bounds__(512, 2) void win_attn_kernel(
    const float* __restrict__ x_g,
    const float* __restrict__ mask_g,
    const float* __restrict__ rpb_g,
    const int* __restrict__ rel_g,
    const float* __restrict__ qkvw_g,
    const float* __restrict__ qkvb_g,
    const float* __restrict__ projw_g,
    const float* __restrict__ projb_g,
    const ushort_t* __restrict__ wbf_g,   // swizzled bf16 weights (MODE>=1)
    const float* __restrict__ bias_g,     // fragment-ordered bias (MODE==2)
    float* __restrict__ out_g)
{
    extern __shared__ char smem[];
    ushort_t* x_lds  = (ushort_t*)(smem + OFF_X);
    ushort_t* q_lds  = (ushort_t*)(smem + OFF_Q);
    ushort_t* k_lds  = (ushort_t*)(smem + OFF_K);
    ushort_t* vT     = (ushort_t*)(smem + OFF_VT);
    ushort_t* P_lds  = (ushort_t*)(smem + OFF_P);
    float*    mask_p = (float*)(smem + OFF_MASK);
    float*    rpb_l  = (float*)(smem + OFF_RPB);
    ushort_t* rel_p  = (ushort_t*)(smem + OFF_REL);
    float*    bq     = (float*)(smem + OFF_BQ);
    float*    bp     = (float*)(smem + OFF_BP);

    const int tid  = threadIdx.x;
    const int b    = blockIdx.x;
    const int wi   = b & 63;           // window index -> mask row
    const int w    = tid >> 6;         // wave id 0..7
    const int lane = tid & 63;
    const int g    = lane >> 4;        // 16-lane group 0..3
    const int c    = lane & 15;        // lane-in-group

    // ---------------- stage ----------------
    {
        const float* xg = x_g + (size_t)b * (NTOK * DIMC);
        for (int i = tid; i < 64 * 24; i += 512) {           // 64 rows x 24 chunks of 8
            int row = i / 24, col = (i % 24) * 8;
            u32x4 v = {0u, 0u, 0u, 0u};
            if (row < NTOK) {
                const float* src = xg + row * DIMC + col;
                f32x4 a = *(const f32x4*)src;
                f32x4 d = *(const f32x4*)(src + 4);
                v[0] = (uint32_t)f2bf(a[0]) | ((uint32_t)f2bf(a[1]) << 16);
                v[1] = (uint32_t)f2bf(a[2]) | ((uint32_t)f2bf(a[3]) << 16);
                v[2] = (uint32_t)f2bf(d[0]) | ((uint32_t)f2bf(d[1]) << 16);
                v[3] = (uint32_t)f2bf(d[2]) | ((uint32_t)f2bf(d[3]) << 16);
            }
            *(u32x4*)&x_lds[row * XS + col] = v;
        }
        if constexpr (MODE < 2) {
            const float* mw = mask_g + (size_t)wi * (NTOK * NTOK);
            for (int i = tid; i < 64 * 64; i += 512) {
                int m = i >> 6, n = i & 63;
                float f;
                if (n >= NTOK)      f = -30000.0f;
                else if (m >= NTOK) f = 0.0f;
                else                f = mw[m * NTOK + n];
                mask_p[m * MS + n] = f;
                rel_p[m * RS + n] = (m < NTOK && n < NTOK) ? (ushort_t)rel_g[m * NTOK + n]
                                                           : (ushort_t)0;
            }
            for (int i = tid; i < 169 * 6; i += 512)
                rpb_l[(i / 6) * 8 + (i % 6)] = rpb_g[i];
        }
        for (int i = tid; i < 576; i += 512) {
            float v = qkvb_g[i];
            if constexpr (MODE == 2) { if (i < 192) v *= SCALE; }
            bq[i] = v;
        }
        if (tid < 192) bp[tid] = projb_g[tid];
    }
    __syncthreads();

    // ---------------- QKV GEMM: [64,192] @ [192,576] ----------------
    // wave (mh = w>>2, cq = w&3): rows [32mh,+32), cols [144cq,+144) = 9 tiles
    {
        const int mh = w >> 2, cq = w & 3;
        const ushort_t* wq = wbf_g + (size_t)cq * (9 * 6 * 64 * 8);

        bf16x8 ring[4][6];
        if constexpr (MODE >= 1) {
            #pragma unroll
            for (int p = 0; p < 3; ++p)
                #pragma unroll
                for (int kk = 0; kk < 6; ++kk)
                    ring[p][kk] = *(const bf16x8*)(wq + (size_t)((p * 6 + kk) * 64 + lane) * 8);
            __builtin_amdgcn_sched_barrier(0);   // pin: prefetch issued first
        }

        bf16x8 ax[2][6];
        #pragma unroll
        for (int mt = 0; mt < 2; ++mt)
            #pragma unroll
            for (int kk = 0; kk < 6; ++kk)
                ax[mt][kk] = *(const bf16x8*)&x_lds[(32 * mh + 16 * mt + c) * XS + kk * 32 + g * 8];

        #pragma unroll
        for (int nt = 0; nt < 9; ++nt) {
            const int cg = 144 * cq + nt * 16 + c;
            bf16x8 bw[6];
            if constexpr (MODE >= 1) {
                if (nt + 3 < 9) {
                    #pragma unroll
                    for (int kk = 0; kk < 6; ++kk)
                        ring[(nt + 3) & 3][kk] =
                            *(const bf16x8*)(wq + (size_t)(((nt + 3) * 6 + kk) * 64 + lane) * 8);
                }
                __builtin_amdgcn_sched_barrier(0);
                #pragma unroll
                for (int kk = 0; kk < 6; ++kk) bw[kk] = ring[nt & 3][kk];
            } else {
                #pragma unroll
                for (int kk = 0; kk < 6; ++kk)
                    bw[kk] = cvt8(qkvw_g + (size_t)cg * DIMC + kk * 32 + g * 8);
            }
            f32x4 z = {0.f, 0.f, 0.f, 0.f};
            f32x4 acc[2] = {z, z};
            #pragma unroll
            for (int kk = 0; kk < 6; ++kk)
                #pragma unroll
                for (int mt = 0; mt < 2; ++mt)
                    acc[mt] = __builtin_amdgcn_mfma_f32_16x16x32_bf16(ax[mt][kk], bw[kk], acc[mt], 0, 0, 0);

            const float bias = bq[cg];
            const int seg = 144 * cq + nt * 16;
            if (seg < 192) {            // q (pre-scaled in MODE2)
                #pragma unroll
                for (int mt = 0; mt < 2; ++mt)
                    #pragma unroll
                    for (int r = 0; r < 4; ++r)
                        q_lds[(32 * mh + 16 * mt + g * 4 + r) * XS + cg] = f2bf(acc[mt][r] + bias);
            } else if (seg < 384) {     // k
                const int ck = cg - 192;
                #pragma unroll
                for (int mt = 0; mt < 2; ++mt)
                    #pragma unroll
                    for (int r = 0; r < 4; ++r)
                        k_lds[(32 * mh + 16 * mt + g * 4 + r) * XS + ck] = f2bf(acc[mt][r] + bias);
            } else {                    // v -> vT[h*32+dim][token]
                const int cv = cg - 384;
                #pragma unroll
                for (int mt = 0; mt < 2; ++mt) {
                    uint32_t lo = (uint32_t)f2bf(acc[mt][0] + bias) | ((uint32_t)f2bf(acc[mt][1] + bias) << 16);
                    uint32_t hi = (uint32_t)f2bf(acc[mt][2] + bias) | ((uint32_t)f2bf(acc[mt][3] + bias) << 16);
                    uint32_t* dst = (uint32_t*)&vT[cv * VTS + 32 * mh + 16 * mt + g * 4];
                    dst[0] = lo; dst[1] = hi;
                }
            }
        }
    }
    __syncthreads();

    // ---------------- attention: wave (wsid = w&3, hh = w>>2): q-strip [16wsid,+16), heads 3hh.. ----
    bf16x8 pw[3][6];
    {
        const int wsid = w & 3, hh = w >> 2;
        ushort_t* Pw = P_lds + w * (16 * PS);
        const int mq0 = 16 * wsid + g * 4;

        auto head = [&](int h) {
            bf16x8 aq = *(const bf16x8*)&q_lds[(16 * wsid + c) * XS + h * HD + g * 8];
            f32x4 S[4];
            if constexpr (MODE == 2) {
                // C-fragment bias: chunk base for (wi,h,wsid), 256 floats per t
                const float* bC = bias_g + ((size_t)((wi * 6 + h) * 4 + wsid) * 4) * 256 + lane * 4;
                #pragma unroll
                for (int t = 0; t < 4; ++t) {
                    f32x4 Ct = *(const f32x4*)(bC + t * 256);
                    bf16x8 bk = *(const bf16x8*)&k_lds[(16 * t + c) * XS + h * HD + g * 8];
                    S[t] = __builtin_amdgcn_mfma_f32_16x16x32_bf16(aq, bk, Ct, 0, 0, 0);
                }
            } else {
                #pragma unroll
                for (int t = 0; t < 4; ++t) {
                    bf16x8 bk = *(const bf16x8*)&k_lds[(16 * t + c) * XS + h * HD + g * 8];
                    f32x4 z = {0.f, 0.f, 0.f, 0.f};
                    S[t] = __builtin_amdgcn_mfma_f32_16x16x32_bf16(aq, bk, z, 0, 0, 0);
                }
            }
            float rinv[4];
            #pragma unroll
            for (int r = 0; r < 4; ++r) {
                float sv[4];
                if constexpr (MODE == 2) {
                    #pragma unroll
                    for (int t = 0; t < 4; ++t) sv[t] = S[t][r];
                } else {
                    const int mq = mq0 + r;
                    const float*    mrow = mask_p + mq * MS;
                    const ushort_t* rrow = rel_p + mq * RS;
                    #pragma unroll
                    for (int t = 0; t < 4; ++t) {
                        const int n = 16 * t + c;
                        sv[t] = S[t][r] * SCALE + rpb_l[(int)rrow[n] * 8 + h] + mrow[n];
                    }
                }
                float vmax = fmaxf(fmaxf(sv[0], sv[1]), fmaxf(sv[2], sv[3]));
                #pragma unroll
                for (int xm = 1; xm < 16; xm <<= 1)
                    vmax = fmaxf(vmax, __shfl_xor(vmax, xm));
                float sum = 0.f;
                float ev[4];
                #pragma unroll
                for (int t = 0; t < 4; ++t) {
                    ev[t] = __expf(fmaxf(sv[t] - vmax, -80.0f));   // NaN firewall
                    sum += ev[t];
                }
                #pragma unroll
                for (int xm = 1; xm < 16; xm <<= 1)
                    sum += __shfl_xor(sum, xm);
                rinv[r] = 1.0f / sum;
                #pragma unroll
                for (int t = 0; t < 4; ++t)                       // unnormalized P
                    Pw[(g * 4 + r) * PS + 16 * t + c] = f2bf(ev[t]);
            }
            // O = P @ V (same-wave LDS dep, no barrier)
            f32x4 z = {0.f, 0.f, 0.f, 0.f};
            f32x4 O[2] = {z, z};
            #pragma unroll
            for (int ks = 0; ks < 2; ++ks) {
                bf16x8 ap = *(const bf16x8*)&Pw[c * PS + ks * 32 + g * 8];
                #pragma unroll
                for (int nt = 0; nt < 2; ++nt) {
                    bf16x8 bv = *(const bf16x8*)&vT[(h * HD + nt * 16 + c) * VTS + ks * 32 + g * 8];
                    O[nt] = __builtin_amdgcn_mfma_f32_16x16x32_bf16(ap, bv, O[nt], 0, 0, 0);
                }
            }
            #pragma unroll
            for (int nt = 0; nt < 2; ++nt)
                #pragma unroll
                for (int r = 0; r < 4; ++r)
                    x_lds[(16 * wsid + g * 4 + r) * XS + h * HD + nt * 16 + c] =
                        f2bf(O[nt][r] * rinv[r]);                 // normalize here
        };

        head(hh * 3 + 0);
        head(hh * 3 + 1);
        if constexpr (MODE >= 1) {       // proj-weight prefetch; covered by head 3
            const int cq4 = w & 3;
            const ushort_t* wp = wbf_g + QKVW_N + (size_t)cq4 * (3 * 6 * 64 * 8);
            #pragma unroll
            for (int nt = 0; nt < 3; ++nt)
                #pragma unroll
                for (int kk = 0; kk < 6; ++kk)
                    pw[nt][kk] = *(const bf16x8*)(wp + (size_t)((nt * 6 + kk) * 64 + lane) * 8);
            __builtin_amdgcn_sched_barrier(0);
        }
        head(hh * 3 + 2);
    }
    __syncthreads();

    // ---------------- proj GEMM: [64,192] @ [192,192] -> direct f32 global store ----------------
    {
        const int mh = w >> 2, cq4 = w & 3;
        bf16x8 aa[2][6];
        #pragma unroll
        for (int mt = 0; mt < 2; ++mt)
            #pragma unroll
            for (int kk = 0; kk < 6; ++kk)
                aa[mt][kk] = *(const bf16x8*)&x_lds[(32 * mh + 16 * mt + c) * XS + kk * 32 + g * 8];

        float* og = out_g + (size_t)b * (NTOK * DIMC);
        #pragma unroll
        for (int nt = 0; nt < 3; ++nt) {
            const int cg = 48 * cq4 + nt * 16 + c;
            bf16x8 bw[6];
            #pragma unroll
            for (int kk = 0; kk < 6; ++kk) {
                if constexpr (MODE >= 1)
                    bw[kk] = pw[nt][kk];
                else
                    bw[kk] = cvt8(projw_g + (size_t)cg * DIMC + kk * 32 + g * 8);
            }
            f32x4 z = {0.f, 0.f, 0.f, 0.f};
            f32x4 acc[2] = {z, z};
            #pragma unroll
            for (int kk = 0; kk < 6; ++kk)
                #pragma unroll
                for (int mt = 0; mt < 2; ++mt)
                    acc[mt] = __builtin_amdgcn_mfma_f32_16x16x32_bf16(aa[mt][kk], bw[kk], acc[mt], 0, 0, 0);
            const float bias = bp[cg];
            #pragma unroll
            for (int mt = 0; mt < 2; ++mt)
                #pragma unroll
                for (int r = 0; r < 4; ++r) {
                    const int row = 32 * mh + 16 * mt + g * 4 + r;
                    if (row < NTOK) og[row * DIMC + cg] = acc[mt][r] + bias;
                }
        }
    }
}

extern "C" void kernel_launch(void* const* d_in, const int* in_sizes, int n_in,
                              void* d_out, int out_size, void* d_ws, size_t ws_size,
                              hipStream_t stream) {
    (void)in_sizes; (void)n_in; (void)out_size;
    const float* x_g     = (const float*)d_in[0];
    const float* mask_g  = (const float*)d_in[1];
    const float* rpb_g   = (const float*)d_in[2];
    const int*   rel_g   = (const int*)d_in[3];
    const float* qkvw_g  = (const float*)d_in[4];
    const float* qkvb_g  = (const float*)d_in[5];
    const float* projw_g = (const float*)d_in[6];
    const float* projb_g = (const float*)d_in[7];
    float*       out_g   = (float*)d_out;

    const bool has_w = (d_ws != nullptr) && (ws_size >= WS_NEED1);
    const bool has_b = (d_ws != nullptr) && (ws_size >= WS_NEED2);
    ushort_t* wbf = (ushort_t*)d_ws;
    float* bias4 = (float*)((char*)d_ws + WBF_BYTES);

    if (has_w) {
        int ngrp = QKV_GRP + PROJ_GRP;
        hipLaunchKernelGGL(swz_weights_kernel, dim3((ngrp + 255) / 256), dim3(256), 0, stream,
                           qkvw_g, projw_g, wbf);
    }
    if (has_b) {
        int nthr = BIAS_FLOATS / 4;
        hipLaunchKernelGGL(bias_kernel, dim3((nthr + 255) / 256), dim3(256), 0, stream,
                           mask_g, rpb_g, rel_g, bias4);
        hipFuncSetAttribute((const void*)win_attn_kernel<2>,
                            hipFuncAttributeMaxDynamicSharedMemorySize, SMEM_BYTES);
        hipLaunchKernelGGL(win_attn_kernel<2>, dim3(4096), dim3(512), SMEM_BYTES, stream,
                           x_g, mask_g, rpb_g, rel_g, qkvw_g, qkvb_g, projw_g, projb_g,
                           wbf, bias4, out_g);
    } else if (has_w) {
        hipFuncSetAttribute((const void*)win_attn_kernel<1>,
                            hipFuncAttributeMaxDynamicSharedMemorySize, SMEM_BYTES);
        hipLaunchKernelGGL(win_attn_kernel<1>, dim3(4096), dim3(512), SMEM_BYTES, stream,
                           x_g, mask_g, rpb_g, rel_g, qkvw_g, qkvb_g, projw_g, projb_g,
                           wbf, (const float*)nullptr, out_g);
    } else {
        hipFuncSetAttribute((const void*)win_attn_kernel<0>,
                            hipFuncAttributeMaxDynamicSharedMemorySize, SMEM_BYTES);
        hipLaunchKernelGGL(win_attn_kernel<0>, dim3(4096), dim3(512), SMEM_BYTES, stream,
                           x_g, mask_g, rpb_g, rel_g, qkvw_g, qkvb_g, projw_g, projb_g,
                           (const ushort_t*)nullptr, (const float*)nullptr, out_g);
    }
}